// Round 3
// baseline (215.096 us; speedup 1.0000x reference)
//
#include <hip/hip_runtime.h>
#include <hip/hip_cooperative_groups.h>

namespace cg = cooperative_groups;

// (B, S, H) = (8, 2048, 1024), fp32.
// Degenerate math: scores == 1/S exactly (softmax of a constant vector);
// context[b,h] == mean_s enc[b,s,h]; decoder_state cancels entirely.
#define BB 8
#define SS 2048
#define HH 1024
#define NCHUNK 128           // S-chunks per batch
#define CHUNK (SS / NCHUNK)  // 16 rows per block
#define NBLK (BB * NCHUNK)   // 1024 blocks

// ---------------- fused cooperative kernel ----------------
// Phase A: block (b,c) sums its 16-row chunk -> partial[b][c][0..1023] (4 MiB).
// grid.sync()
// Phase B: block g reduces 8 outputs (128 partials each) + writes 16 scores.
__global__ void __launch_bounds__(256, 4)
att_fused_kernel(const float* __restrict__ enc, float* __restrict__ partial,
                 float* __restrict__ out) {
    cg::grid_group grid = cg::this_grid();
    const int g = blockIdx.x;
    const int t = threadIdx.x;

    // ---- Phase A ----
    {
        int b = g >> 7;            // / NCHUNK
        int c = g & (NCHUNK - 1);
        const float4* p =
            (const float4*)(enc + ((size_t)b * SS + (size_t)c * CHUNK) * HH) + t;
        float4 v[CHUNK];
        #pragma unroll
        for (int s = 0; s < CHUNK; ++s) v[s] = p[(size_t)s * (HH / 4)];
        #pragma unroll
        for (int stride = CHUNK / 2; stride > 0; stride >>= 1) {
            #pragma unroll
            for (int s = 0; s < stride; ++s) {
                v[s].x += v[s + stride].x;
                v[s].y += v[s + stride].y;
                v[s].z += v[s + stride].z;
                v[s].w += v[s + stride].w;
            }
        }
        ((float4*)(partial + ((size_t)b * NCHUNK + c) * HH))[t] = v[0];
    }

    __threadfence();
    grid.sync();

    // ---- Phase B ----
    // Block g owns context outputs o = g*8 .. g*8+7 (same b for all 8).
    {
        int b = g >> 7;                 // (g*8)/1024
        int h_base = (g & 127) * 8;
        int c0 = t >> 3;                // 0..31
        int hl = t & 7;
        const float* p = partial + ((size_t)b * NCHUNK) * HH + h_base + hl;
        float acc = p[(size_t)(c0) * HH]
                  + p[(size_t)(c0 + 32) * HH]
                  + p[(size_t)(c0 + 64) * HH]
                  + p[(size_t)(c0 + 96) * HH];
        // butterfly all-reduce over the 8 lanes sharing hl within the wave
        acc += __shfl_xor(acc, 8);
        acc += __shfl_xor(acc, 16);
        acc += __shfl_xor(acc, 32);
        __shared__ float lds[4][8];
        int wave = t >> 6, lane = t & 63;
        if (lane < 8) lds[wave][lane] = acc;
        __syncthreads();
        if (t < 8) {
            float s = lds[0][t] + lds[1][t] + lds[2][t] + lds[3][t];
            out[g * 8 + t] = s * (1.0f / SS);
        }
        // scores: 16384 elems starting at 8192; 16 per block
        if (t >= 32 && t < 48) {
            out[BB * HH + g * 16 + (t - 32)] = 1.0f / SS;
        }
    }
}

// ---------------- fallback (non-cooperative) path ----------------
__global__ void __launch_bounds__(256)
att_partial_kernel(const float* __restrict__ enc, float* __restrict__ partial) {
    int blk = blockIdx.x;
    int b = blk >> 7;
    int c = blk & (NCHUNK - 1);
    int t = threadIdx.x;
    const float4* p =
        (const float4*)(enc + ((size_t)b * SS + (size_t)c * CHUNK) * HH) + t;
    float4 v[CHUNK];
    #pragma unroll
    for (int s = 0; s < CHUNK; ++s) v[s] = p[(size_t)s * (HH / 4)];
    #pragma unroll
    for (int stride = CHUNK / 2; stride > 0; stride >>= 1) {
        #pragma unroll
        for (int s = 0; s < stride; ++s) {
            v[s].x += v[s + stride].x;
            v[s].y += v[s + stride].y;
            v[s].z += v[s + stride].z;
            v[s].w += v[s + stride].w;
        }
    }
    ((float4*)(partial + ((size_t)b * NCHUNK + c) * HH))[t] = v[0];
}

__global__ void __launch_bounds__(256)
att_finalize_kernel(const float* __restrict__ partial, float* __restrict__ out) {
    int tid = blockIdx.x * blockDim.x + threadIdx.x;
    if (tid < BB * HH) {
        int b = tid >> 10;
        int h = tid & (HH - 1);
        const float* p = partial + (size_t)b * NCHUNK * HH + h;
        float acc = 0.f;
        #pragma unroll 8
        for (int c = 0; c < NCHUNK; ++c) acc += p[(size_t)c * HH];
        out[tid] = acc * (1.0f / SS);
    } else if (tid < BB * HH + BB * SS) {
        out[tid] = 1.0f / SS;
    }
}

__global__ void __launch_bounds__(256)
att_direct_kernel(const float* __restrict__ enc, float* __restrict__ out) {
    int tid = blockIdx.x * blockDim.x + threadIdx.x;
    if (tid < BB * HH) {
        int b = tid >> 10;
        int h = tid & (HH - 1);
        const float* p = enc + (size_t)b * SS * HH + h;
        float acc = 0.f;
        for (int s = 0; s < SS; ++s) acc += p[(size_t)s * HH];
        out[tid] = acc * (1.0f / SS);
    } else if (tid < BB * HH + BB * SS) {
        out[tid] = 1.0f / SS;
    }
}

extern "C" void kernel_launch(void* const* d_in, const int* in_sizes, int n_in,
                              void* d_out, int out_size, void* d_ws, size_t ws_size,
                              hipStream_t stream) {
    const float* enc = (const float*)d_in[1];  // encoder_outputs (B,S,H)
    float* out = (float*)d_out;                // [context (B*H) | scores (B*S)]

    const int total_out = BB * HH + BB * SS;          // 24576
    const int fin_blocks = (total_out + 255) / 256;   // 96
    const size_t part_bytes = (size_t)BB * NCHUNK * HH * sizeof(float);  // 4 MiB

    if (d_ws != nullptr && ws_size >= part_bytes) {
        float* partial = (float*)d_ws;
        void* args[] = {(void*)&enc, (void*)&partial, (void*)&out};
        hipError_t err = hipLaunchCooperativeKernel(
            (const void*)att_fused_kernel, dim3(NBLK), dim3(256), args, 0, stream);
        if (err != hipSuccess) {
            // fallback: two-kernel path
            att_partial_kernel<<<NBLK, 256, 0, stream>>>(enc, partial);
            att_finalize_kernel<<<fin_blocks, 256, 0, stream>>>(partial, out);
        }
    } else {
        att_direct_kernel<<<fin_blocks, 256, 0, stream>>>(enc, out);
    }
}

// Round 4
// 27.198 us; speedup vs baseline: 7.9087x; 7.9087x over previous
//
#include <hip/hip_runtime.h>

// (B, S, H) = (8, 2048, 1024), fp32.
// Degenerate math: scores == 1/S exactly (softmax of a constant vector);
// context[b,h] == mean_s enc[b,s,h]; decoder_state cancels entirely.
// Strategy: single streaming kernel, block-local column sums over a 32-row
// chunk, scaled atomicAdd into the (pre-zeroed) context region of d_out.
// NOTE (R2 lesson): cooperative grid.sync() costs ~200us on MI355X — avoid.
#define BB 8
#define SS 2048
#define HH 1024
#define CPB 64                 // chunk-blocks per batch
#define ROWS (SS / CPB)        // 32 rows per block
#define NBLK (BB * CPB)        // 512 blocks
#define SCORES_PER_BLK ((BB * SS) / NBLK)  // 32

__global__ void __launch_bounds__(256)
att_atomic_kernel(const float* __restrict__ enc, float* __restrict__ out) {
    const int g = blockIdx.x;
    const int b = g >> 6;            // / CPB
    const int c = g & (CPB - 1);
    const int t = threadIdx.x;       // 0..255, owns float4 column 4t..4t+3

    const float4* p =
        (const float4*)(enc + ((size_t)b * SS + (size_t)c * ROWS) * HH) + t;

    float4 acc = make_float4(0.f, 0.f, 0.f, 0.f);
    // Two fully-unrolled 16-deep load batches: 16 independent float4 loads
    // in flight per thread (deep MLP is what saturates HBM on gfx950).
    #pragma unroll
    for (int pass = 0; pass < 2; ++pass) {
        float4 v[16];
        #pragma unroll
        for (int s = 0; s < 16; ++s)
            v[s] = p[(size_t)(pass * 16 + s) * (HH / 4)];
        #pragma unroll
        for (int stride = 8; stride > 0; stride >>= 1) {
            #pragma unroll
            for (int s = 0; s < stride; ++s) {
                v[s].x += v[s + stride].x;
                v[s].y += v[s + stride].y;
                v[s].z += v[s + stride].z;
                v[s].w += v[s + stride].w;
            }
        }
        acc.x += v[0].x; acc.y += v[0].y; acc.z += v[0].z; acc.w += v[0].w;
    }

    const float inv = 1.0f / SS;
    float* o = out + (size_t)b * HH + 4 * t;
    atomicAdd(o + 0, acc.x * inv);
    atomicAdd(o + 1, acc.y * inv);
    atomicAdd(o + 2, acc.z * inv);
    atomicAdd(o + 3, acc.w * inv);

    // scores: BB*SS elems starting at BB*HH; 32 per block, plain writes.
    if (t < SCORES_PER_BLK) {
        out[BB * HH + g * SCORES_PER_BLK + t] = inv;
    }
}

extern "C" void kernel_launch(void* const* d_in, const int* in_sizes, int n_in,
                              void* d_out, int out_size, void* d_ws, size_t ws_size,
                              hipStream_t stream) {
    const float* enc = (const float*)d_in[1];  // encoder_outputs (B,S,H)
    float* out = (float*)d_out;                // [context (B*H) | scores (B*S)]

    // Zero the atomic-accumulated context region every launch (d_out is
    // poisoned once and never re-poisoned between replays).
    hipMemsetAsync(out, 0, (size_t)BB * HH * sizeof(float), stream);
    att_atomic_kernel<<<NBLK, 256, 0, stream>>>(enc, out);
}

// Round 5
// 19.510 us; speedup vs baseline: 11.0248x; 1.3940x over previous
//
#include <hip/hip_runtime.h>

// (B, S, H) = (8, 2048, 1024), fp32.
// Degenerate math: scores == 1/S exactly (softmax of a constant vector);
// context[b,h] == mean_s enc[b,s,h]; decoder_state cancels entirely.
// Lessons: R2 — grid.sync() costs ~200us on MI355X, never for short kernels.
//          R3 — 512K contended fp32 atomics + memset node cost ~4us vs R1.
#define BB 8
#define SS 2048
#define HH 1024
#define NCHUNK 128           // S-chunks per batch
#define CHUNK (SS / NCHUNK)  // 16 rows per block
#define NBLK (BB * NCHUNK)   // 1024 blocks

// Kernel A (unchanged from R1, best measured): block (b,c) sums its 16-row
// chunk with 16 fully-unrolled independent float4 loads per thread.
__global__ void __launch_bounds__(256)
att_partial_kernel(const float* __restrict__ enc, float* __restrict__ partial) {
    int blk = blockIdx.x;
    int b = blk >> 7;          // / NCHUNK
    int c = blk & (NCHUNK - 1);
    int t = threadIdx.x;
    const float4* p =
        (const float4*)(enc + ((size_t)b * SS + (size_t)c * CHUNK) * HH) + t;
    float4 v[CHUNK];
    #pragma unroll
    for (int s = 0; s < CHUNK; ++s) v[s] = p[(size_t)s * (HH / 4)];
    #pragma unroll
    for (int stride = CHUNK / 2; stride > 0; stride >>= 1) {
        #pragma unroll
        for (int s = 0; s < stride; ++s) {
            v[s].x += v[s + stride].x;
            v[s].y += v[s + stride].y;
            v[s].z += v[s + stride].z;
            v[s].w += v[s + stride].w;
        }
    }
    ((float4*)(partial + ((size_t)b * NCHUNK + c) * HH))[t] = v[0];
}

// Kernel B (rewritten): 128 blocks x 256 threads. Block = (b, 64-wide h
// slice). Wave w (=t>>6) sums c = w*32..w*32+31 for its 64 h's — each wave
// iteration reads 64 consecutive floats (256 B, coalesced). LDS[4][64]
// cross-wave reduce, 64 context writes + 128 score fills per block.
__global__ void __launch_bounds__(256)
att_finalize_kernel(const float* __restrict__ partial, float* __restrict__ out) {
    const int blk = blockIdx.x;        // 0..127
    const int b = blk >> 4;            // / 16
    const int hbase = (blk & 15) * 64;
    const int t = threadIdx.x;
    const int hl = t & 63;
    const int cq = t >> 6;             // 0..3

    const float* p = partial + ((size_t)(b * NCHUNK + cq * 32)) * HH + hbase + hl;
    float acc = 0.f;
    #pragma unroll 8
    for (int c = 0; c < 32; ++c) acc += p[(size_t)c * HH];

    // score fill (independent of the reduction; before the barrier)
    const float inv = 1.0f / SS;
    if (t >= 64 && t < 192) {
        out[BB * HH + blk * 128 + (t - 64)] = inv;
    }

    __shared__ float lds[4][64];
    lds[cq][hl] = acc;
    __syncthreads();
    if (t < 64) {
        float s = lds[0][t] + lds[1][t] + lds[2][t] + lds[3][t];
        out[b * HH + hbase + t] = s * inv;
    }
}

// Fallback (workspace too small): direct full-column sums.
__global__ void __launch_bounds__(256)
att_direct_kernel(const float* __restrict__ enc, float* __restrict__ out) {
    int tid = blockIdx.x * blockDim.x + threadIdx.x;
    if (tid < BB * HH) {
        int b = tid >> 10;
        int h = tid & (HH - 1);
        const float* p = enc + (size_t)b * SS * HH + h;
        float acc = 0.f;
        for (int s = 0; s < SS; ++s) acc += p[(size_t)s * HH];
        out[tid] = acc * (1.0f / SS);
    } else if (tid < BB * HH + BB * SS) {
        out[tid] = 1.0f / SS;
    }
}

extern "C" void kernel_launch(void* const* d_in, const int* in_sizes, int n_in,
                              void* d_out, int out_size, void* d_ws, size_t ws_size,
                              hipStream_t stream) {
    const float* enc = (const float*)d_in[1];  // encoder_outputs (B,S,H)
    float* out = (float*)d_out;                // [context (B*H) | scores (B*S)]

    const size_t part_bytes = (size_t)BB * NCHUNK * HH * sizeof(float);  // 4 MiB
    if (d_ws != nullptr && ws_size >= part_bytes) {
        float* partial = (float*)d_ws;
        att_partial_kernel<<<NBLK, 256, 0, stream>>>(enc, partial);
        att_finalize_kernel<<<128, 256, 0, stream>>>(partial, out);
    } else {
        const int total_out = BB * HH + BB * SS;
        att_direct_kernel<<<(total_out + 255) / 256, 256, 0, stream>>>(enc, out);
    }
}